// Round 20
// baseline (89.202 us; speedup 1.0000x reference)
//
#include <hip/hip_runtime.h>

#define D1 96
#define GRID_VOX (D1 * D1 * D1)
#define CAP2S 8   // per-(voxel,s) conv2 pairs (max 7 exact)
#define OS 68     // oT row stride in floats (bank-conflict pad, 16B aligned)

typedef __attribute__((ext_vector_type(8))) short short8_t;  // 8 bf16
typedef __attribute__((ext_vector_type(4))) float f32x4;

__device__ __forceinline__ unsigned short bf16rne(float x) {
    unsigned u = __float_as_uint(x);
    return (unsigned short)((u + 0x7FFF + ((u >> 16) & 1)) >> 16);
}
__device__ __forceinline__ void split2(float v, unsigned short& hi,
                                       unsigned short& lo) {
    hi = bf16rne(v);
    float hf = __uint_as_float((unsigned)hi << 16);
    lo = bf16rne(v - hf);
}
__device__ __forceinline__ float silu(float v) {
    return v / (1.f + __expf(-v));
}

// ---------------------------------------------------------------------------
// setup: one kernel, disjoint thread ranges (no ordering deps):
//  [0,512)            pack conv1 self-tap B-fragments (bf16 hi/lo)
//  [512,4608)         pack conv2 per-child folded B-fragments
//  [4608,266752)      fold fp32 conv2 fixup weights W2e
//  [266752,266752+n)  scatter grid[cell] = i+1  (no zero-fill: readers
//                     validate entries via exact coords match)
// ---------------------------------------------------------------------------
__global__ void setup_kernel(const float* __restrict__ W1,
                             const float* __restrict__ W2,
                             const int* __restrict__ coords,
                             unsigned short* __restrict__ grid,
                             unsigned short* __restrict__ Wpk1h,
                             unsigned short* __restrict__ Wpk1l,
                             unsigned short* __restrict__ Wpk2h,
                             unsigned short* __restrict__ Wpk2l,
                             float* __restrict__ W2e, int n) {
    int t = blockIdx.x * blockDim.x + threadIdx.x;
    if (t < 512) {  // conv1 B-fragments: W1[13] self tap
        int fid = t >> 6, l = t & 63;
        int kb = fid >> 2, c = fid & 3;
#pragma unroll
        for (int e = 0; e < 8; ++e) {
            int ci = kb * 32 + ((l >> 4) << 3) + e;
            int co = c * 16 + (l & 15);
            unsigned short hi, lo;
            split2(W1[13 * 4096 + ci * 64 + co], hi, lo);
            Wpk1h[(size_t)t * 8 + e] = hi;
            Wpk1l[(size_t)t * 8 + e] = lo;
        }
    } else if (t < 4608) {  // conv2 dense (self-parent fold) fragments
        int u = t - 512;
        int fid = u >> 6, l = u & 63;
        int s = fid >> 3, kb = (fid >> 2) & 1, c = fid & 3;
        int s0 = (s >> 2) & 1, s1 = (s >> 1) & 1, s2 = s & 1;
#pragma unroll
        for (int e = 0; e < 8; ++e) {
            int ci = kb * 32 + ((l >> 4) << 3) + e;
            int co = c * 16 + (l & 15);
            float sum = 0.f;
            for (int o0 = -s0; o0 <= 1 - s0; ++o0)
                for (int o1 = -s1; o1 <= 1 - s1; ++o1)
                    for (int o2 = -s2; o2 <= 1 - s2; ++o2) {
                        int k = (o0 + 1) * 9 + (o1 + 1) * 3 + (o2 + 1);
                        sum += W2[k * 4096 + ci * 64 + co];
                    }
            unsigned short hi, lo;
            split2(sum, hi, lo);
            Wpk2h[(size_t)u * 8 + e] = hi;
            Wpk2l[(size_t)u * 8 + e] = lo;
        }
    } else if (t < 4608 + 262144) {  // W2e fp32 fixup weights
        int r = t - 4608;
        int sd = r >> 12, e = r & 4095;
        int s = sd >> 3, d = sd & 7;
        int sa[3] = { (s >> 2) & 1, (s >> 1) & 1, s & 1 };
        int da[3] = { (d >> 2) & 1, (d >> 1) & 1, d & 1 };
        int lo_[3], hi_[3];
        for (int a = 0; a < 3; ++a) {
            int p = sa[a] - 1 + da[a];
            int l = 2 * p - sa[a];     if (l < -1) l = -1;
            int h = 2 * p + 1 - sa[a]; if (h > 1) h = 1;
            lo_[a] = l; hi_[a] = h;
        }
        float sum = 0.f;
        for (int o0 = lo_[0]; o0 <= hi_[0]; ++o0)
            for (int o1 = lo_[1]; o1 <= hi_[1]; ++o1)
                for (int o2 = lo_[2]; o2 <= hi_[2]; ++o2) {
                    int k = (o0 + 1) * 9 + (o1 + 1) * 3 + (o2 + 1);
                    sum += W2[k * 4096 + e];
                }
        W2e[(size_t)sd * 4096 + e] = sum;
    } else {  // scatter
        int i = t - (4608 + 262144);
        if (i < n)
            grid[(coords[3 * i] * D1 + coords[3 * i + 1]) * D1 +
                 coords[3 * i + 2]] = (unsigned short)(i + 1);
    }
}

// ---------------------------------------------------------------------------
__device__ __forceinline__ void load_split_A(const float* __restrict__ src,
                                             int arow, int lane, short8_t& ah0,
                                             short8_t& al0, short8_t& ah1,
                                             short8_t& al1) {
    const float* ap = src + (size_t)arow * 64 + ((lane >> 4) << 3);
    f32x4 a0 = *(const f32x4*)(ap);
    f32x4 a1 = *(const f32x4*)(ap + 4);
    f32x4 a2 = *(const f32x4*)(ap + 32);
    f32x4 a3 = *(const f32x4*)(ap + 36);
#pragma unroll
    for (int e = 0; e < 4; ++e) {
        unsigned short hh, ll;
        split2(a0[e], hh, ll); ah0[e] = (short)hh; al0[e] = (short)ll;
        split2(a1[e], hh, ll); ah0[4 + e] = (short)hh; al0[4 + e] = (short)ll;
        split2(a2[e], hh, ll); ah1[e] = (short)hh; al1[e] = (short)ll;
        split2(a3[e], hh, ll); ah1[4 + e] = (short)hh; al1[4 + e] = (short)ll;
    }
}

// ---------------------------------------------------------------------------
// 4-col-tile dense: wave covers rows [wl*16,+16) x ALL 4 col-tiles (24 MFMAs).
// ---------------------------------------------------------------------------
__device__ __forceinline__ void dense_mfma4(const short8_t ah0, const short8_t al0,
                                            const short8_t ah1, const short8_t al1,
                                            const short8_t* __restrict__ Bh,
                                            const short8_t* __restrict__ Bl,
                                            const float* __restrict__ bias,
                                            float* __restrict__ oT, int wl,
                                            int lane) {
#pragma unroll 1
    for (int c = 0; c < 4; ++c) {
        short8_t bh0 = Bh[c * 64 + lane];
        short8_t bl0 = Bl[c * 64 + lane];
        short8_t bh1 = Bh[(4 + c) * 64 + lane];
        short8_t bl1 = Bl[(4 + c) * 64 + lane];
        f32x4 acc = {0.f, 0.f, 0.f, 0.f};
        acc = __builtin_amdgcn_mfma_f32_16x16x32_bf16(ah0, bh0, acc, 0, 0, 0);
        acc = __builtin_amdgcn_mfma_f32_16x16x32_bf16(al0, bh0, acc, 0, 0, 0);
        acc = __builtin_amdgcn_mfma_f32_16x16x32_bf16(ah0, bl0, acc, 0, 0, 0);
        acc = __builtin_amdgcn_mfma_f32_16x16x32_bf16(ah1, bh1, acc, 0, 0, 0);
        acc = __builtin_amdgcn_mfma_f32_16x16x32_bf16(al1, bh1, acc, 0, 0, 0);
        acc = __builtin_amdgcn_mfma_f32_16x16x32_bf16(ah1, bl1, acc, 0, 0, 0);
        int col = c * 16 + (lane & 15);
        float bb = bias[col];
#pragma unroll
        for (int r = 0; r < 4; ++r) {
            int row = wl * 16 + ((lane >> 4) << 2) + r;
            oT[row * OS + col] = acc[r] + bb;
        }
    }
}

// 2-col-tile dense for conv1's 8-wave layout (wave w: rows (w&3)*16,
// col-tiles {2*(w>>2),+1}) — round-18 structure.
__device__ __forceinline__ void dense_mfma8(const short8_t ah0, const short8_t al0,
                                            const short8_t ah1, const short8_t al1,
                                            const short8_t* __restrict__ Bh,
                                            const short8_t* __restrict__ Bl,
                                            const float* __restrict__ bias,
                                            float* __restrict__ oT, int w,
                                            int lane) {
    int c0 = (w >> 2) * 2;
#pragma unroll
    for (int cc = 0; cc < 2; ++cc) {
        int c = c0 + cc;
        short8_t bh0 = Bh[c * 64 + lane];
        short8_t bl0 = Bl[c * 64 + lane];
        short8_t bh1 = Bh[(4 + c) * 64 + lane];
        short8_t bl1 = Bl[(4 + c) * 64 + lane];
        f32x4 acc = {0.f, 0.f, 0.f, 0.f};
        acc = __builtin_amdgcn_mfma_f32_16x16x32_bf16(ah0, bh0, acc, 0, 0, 0);
        acc = __builtin_amdgcn_mfma_f32_16x16x32_bf16(al0, bh0, acc, 0, 0, 0);
        acc = __builtin_amdgcn_mfma_f32_16x16x32_bf16(ah0, bl0, acc, 0, 0, 0);
        acc = __builtin_amdgcn_mfma_f32_16x16x32_bf16(ah1, bh1, acc, 0, 0, 0);
        acc = __builtin_amdgcn_mfma_f32_16x16x32_bf16(al1, bh1, acc, 0, 0, 0);
        acc = __builtin_amdgcn_mfma_f32_16x16x32_bf16(ah1, bl1, acc, 0, 0, 0);
        int col = c * 16 + (lane & 15);
        float bb = bias[col];
#pragma unroll
        for (int r = 0; r < 4; ++r) {
            int row = (w & 3) * 16 + ((lane >> 4) << 2) + r;
            oT[row * OS + col] = acc[r] + bb;
        }
    }
}

// wave-scan helper: counts -> excl prefix + total, stored in LDS
__device__ __forceinline__ void scan64(int cnt, int lane, int* pfxs, int* cnts,
                                       int* nps) {
    int val = cnt;
#pragma unroll
    for (int off = 1; off < 64; off <<= 1) {
        int v2 = __shfl_up(val, off);
        if (lane >= off) val += v2;
    }
    pfxs[lane] = val - cnt;
    cnts[lane] = cnt;
    if (lane == 63) nps[0] = val;
}

// ---------------------------------------------------------------------------
// Barrier-free per-wave fixup loop; pairs striped by (stride); oT stride OS.
// ---------------------------------------------------------------------------
__device__ __forceinline__ void fixup_loop(const float* __restrict__ src,
                                           const float* __restrict__ Wbase,
                                           const int* __restrict__ pl, int np,
                                           float* __restrict__ myfsc,
                                           float* __restrict__ oT, int w0,
                                           int stride, int lane) {
    int it = 0;
#pragma unroll 1
    for (int p = w0; p < np; p += stride, ++it) {
        int e = pl[p];
        int j = e & 0x1FFFF, tag = (e >> 17) & 31, row = (e >> 23) & 63;
        float fv = src[(size_t)j * 64 + lane];  // coalesced 256B row
        int buf = it & 1;
        myfsc[buf * 64 + lane] = fv;
        const float* wk = Wbase + (size_t)tag * 4096;  // [ci][co]
        float a0 = 0.f, a1 = 0.f, a2 = 0.f, a3 = 0.f;
#pragma unroll
        for (int c4 = 0; c4 < 16; ++c4) {
            f32x4 fb = *(f32x4*)&myfsc[buf * 64 + c4 * 4];  // ds broadcast
            a0 += fb[0] * wk[(c4 * 4 + 0) * 64 + lane];
            a1 += fb[1] * wk[(c4 * 4 + 1) * 64 + lane];
            a2 += fb[2] * wk[(c4 * 4 + 2) * 64 + lane];
            a3 += fb[3] * wk[(c4 * 4 + 3) * 64 + lane];
        }
        atomicAdd(&oT[row * OS + lane], (a0 + a1) + (a2 + a3));
    }
}

// ---------------------------------------------------------------------------
// conv1 fused (round-18 structure, unchanged): 8 waves, inline pair build.
// ---------------------------------------------------------------------------
__global__ __launch_bounds__(512) void conv1_fused_kernel(
    const int* __restrict__ coords, const float* __restrict__ feats,
    const float* __restrict__ W1, const unsigned short* __restrict__ Wpk1h,
    const unsigned short* __restrict__ Wpk1l, const float* __restrict__ b1,
    const unsigned short* __restrict__ grid, int* __restrict__ c2s,
    int* __restrict__ p2s, float* __restrict__ h, int n) {
    __shared__ __align__(16) float oT[64 * OS];
    __shared__ __align__(16) float fsc[8][2][64];
    __shared__ int plt[64 * 26];
    __shared__ int pl[1664];
    __shared__ int pfxs[64], cnts_s[64], nps[1];
    int base = blockIdx.x * 64;
    int t = threadIdx.x, w = t >> 6, lane = t & 63;

    if (t < 64) {  // inline pair build with validated grid reads
        int myv = base + t;
        int cnt = 0;
        if (myv < n) {
            int c0 = coords[3 * myv], c1v = coords[3 * myv + 1],
                c2v = coords[3 * myv + 2];
            int n2[8] = {0, 0, 0, 0, 0, 0, 0, 0};
#pragma unroll 1
            for (int g = 0; g < 3; ++g) {
                int jv9[9];
                int kb = g * 9;
#pragma unroll
                for (int u = 0; u < 9; ++u) {
                    int k = kb + u;
                    int o0 = k / 9 - 1, o1 = (k / 3) % 3 - 1, o2 = k % 3 - 1;
                    int x0 = c0 + o0, x1 = c1v + o1, x2 = c2v + o2;
                    bool inb = (unsigned)x0 < D1 && (unsigned)x1 < D1 &&
                               (unsigned)x2 < D1;
                    jv9[u] = inb ? (int)grid[(x0 * D1 + x1) * D1 + x2] : 0;
                }
#pragma unroll
                for (int u = 0; u < 9; ++u) {
                    int k = kb + u;
                    if (k == 13) continue;
                    int j1 = jv9[u];
                    if (j1 < 1 || j1 > n) continue;  // poison/garbage reject
                    int o0 = k / 9 - 1, o1 = (k / 3) % 3 - 1, o2 = k % 3 - 1;
                    int x0 = c0 + o0, x1 = c1v + o1, x2 = c2v + o2;
                    int jj = j1 - 1;
                    if (coords[3 * jj] != x0 || coords[3 * jj + 1] != x1 ||
                        coords[3 * jj + 2] != x2)
                        continue;
                    plt[t * 26 + cnt] = jj | (k << 17);
                    ++cnt;
#pragma unroll
                    for (int s = 0; s < 8; ++s) {
                        int d0 = o0 + 1 - ((s >> 2) & 1);
                        int d1 = o1 + 1 - ((s >> 1) & 1);
                        int d2 = o2 + 1 - (s & 1);
                        if (((d0 | d1 | d2) & ~1) == 0) {
                            int d = (d0 << 2) | (d1 << 1) | d2;
                            p2s[((size_t)myv * 8 + s) * CAP2S + n2[s]] =
                                jj | (d << 17);
                            ++n2[s];
                        }
                    }
                }
            }
#pragma unroll
            for (int s = 0; s < 8; ++s) c2s[myv * 8 + s] = n2[s];
        }
        scan64(cnt, lane, pfxs, cnts_s, nps);
    }

    int arow = base + (w & 3) * 16 + (lane & 15);
    if (arow >= n) arow = n - 1;
    short8_t ah0, al0, ah1, al1;
    load_split_A(feats, arow, lane, ah0, al0, ah1, al1);
    dense_mfma8(ah0, al0, ah1, al1, (const short8_t*)Wpk1h,
                (const short8_t*)Wpk1l, b1, oT, w, lane);
    __syncthreads();

    {   // parallel compaction: 8 threads per row
        int row = t & 63, e0 = t >> 6;
        int cr = cnts_s[row], pf = pfxs[row];
        for (int e = e0; e < cr; e += 8)
            pl[pf + e] = plt[row * 26 + e] | (row << 23);
    }
    __syncthreads();

    fixup_loop(feats, W1, pl, nps[0], &fsc[w][0][0], oT, w, 8, lane);
    __syncthreads();

    {   // SiLU + coalesced store
        int r = t >> 3, c8 = (t & 7) * 8;
        if (base + r < n) {
#pragma unroll
            for (int jj = 0; jj < 2; ++jj) {
                f32x4 v = *(f32x4*)&oT[r * OS + c8 + jj * 4];
#pragma unroll
                for (int u = 0; u < 4; ++u) v[u] = silu(v[u]);
                *(f32x4*)&h[(size_t)(base + r) * 64 + c8 + jj * 4] = v;
            }
        }
    }
}

// ---------------------------------------------------------------------------
// conv2 fused: grid (nblk, 4), 512 threads = 2 children per block.
// Waves 0-3 -> child s0 = 2*y, waves 4-7 -> child s0+1. A loaded once per
// (block,row-group) instead of twice; per-block overheads amortized over 2
// children. Each wave: 16 rows x 4 col-tiles (24 MFMAs).
// ---------------------------------------------------------------------------
__global__ __launch_bounds__(512) void conv2_fused_kernel(
    const float* __restrict__ h, const unsigned short* __restrict__ Wpk2h,
    const unsigned short* __restrict__ Wpk2l, const float* __restrict__ W2e,
    const float* __restrict__ b2, const int* __restrict__ c2s,
    const int* __restrict__ p2s, float* __restrict__ out, int n) {
    __shared__ __align__(16) float oT[2][64 * OS];
    __shared__ __align__(16) float fsc[8][2][64];
    __shared__ int pl[2][448];
    __shared__ int pfxs[2][64], cnts_s[2][64], nps[2];
    int base = blockIdx.x * 64;
    int s0 = blockIdx.y * 2;
    int t = threadIdx.x, w = t >> 6, lane = t & 63;
    int sg = w >> 2, wl = w & 3;  // child group, wave-in-group
    int s = s0 + sg;

    // two parallel scans: wave 0 -> child 0, wave 4 -> child 1
    if (wl == 0) {
        int cnt = (base + lane < n) ? c2s[(size_t)(base + lane) * 8 + s] : 0;
        scan64(cnt, lane, pfxs[sg], cnts_s[sg], &nps[sg]);
    }

    int arow = base + wl * 16 + (lane & 15);
    if (arow >= n) arow = n - 1;
    short8_t ah0, al0, ah1, al1;
    load_split_A(h, arow, lane, ah0, al0, ah1, al1);
    dense_mfma4(ah0, al0, ah1, al1,
                (const short8_t*)Wpk2h + (size_t)s * 8 * 64,
                (const short8_t*)Wpk2l + (size_t)s * 8 * 64, b2, oT[sg], wl,
                lane);
    __syncthreads();

    {   // parallel compaction: 256 threads per child, 4 per row
        int child = t >> 8, row = (t >> 2) & 63, e0 = t & 3;
        int cr = cnts_s[child][row], pf = pfxs[child][row];
        int sc = s0 + child;
        for (int e = e0; e < cr; e += 4)
            pl[child][pf + e] =
                p2s[((size_t)(base + row) * 8 + sc) * CAP2S + e] | (row << 23);
    }
    __syncthreads();

    fixup_loop(h, W2e + (size_t)s * 8 * 4096, pl[sg], nps[sg], &fsc[w][0][0],
               oT[sg], wl, 4, lane);
    __syncthreads();

    {   // SiLU + coalesced store: 256 threads per child
        int child = t >> 8, tid = t & 255;
        int r = tid >> 2, c16 = (tid & 3) * 16;
        if (base + r < n) {
            size_t orow = ((size_t)(base + r) * 8 + s0 + child) * 64;
#pragma unroll
            for (int jj = 0; jj < 4; ++jj) {
                f32x4 v = *(f32x4*)&oT[child][r * OS + c16 + jj * 4];
#pragma unroll
                for (int u = 0; u < 4; ++u) v[u] = silu(v[u]);
                *(f32x4*)&out[orow + c16 + jj * 4] = v;
            }
        }
    }
}

// ---------------------------------------------------------------------------
extern "C" void kernel_launch(void* const* d_in, const int* in_sizes, int n_in,
                              void* d_out, int out_size, void* d_ws,
                              size_t ws_size, hipStream_t stream) {
    const int* coords = (const int*)d_in[0];
    const float* feats = (const float*)d_in[1];
    const float* W1 = (const float*)d_in[2];
    const float* b1 = (const float*)d_in[3];
    const float* W2 = (const float*)d_in[4];
    const float* b2 = (const float*)d_in[5];
    float* out = (float*)d_out;

    int n = in_sizes[0] / 3;  // 20000
    int nblk = (n + 63) / 64; // 313

    char* ws = (char*)d_ws;
    size_t off = 0;
    auto alloc = [&](size_t bytes) {
        size_t o = off;
        off = (off + bytes + 255) & ~(size_t)255;
        return o;
    };
    unsigned short* grid1 = (unsigned short*)(ws + alloc((size_t)GRID_VOX * 2));
    float* h      = (float*)(ws + alloc((size_t)n * 64 * 4));     // 5.12 MB
    float* W2e    = (float*)(ws + alloc(64 * 4096 * 4));          // 1 MB
    unsigned short* Wpk1h = (unsigned short*)(ws + alloc(512 * 8 * 2));
    unsigned short* Wpk1l = (unsigned short*)(ws + alloc(512 * 8 * 2));
    unsigned short* Wpk2h = (unsigned short*)(ws + alloc(4096 * 8 * 2));
    unsigned short* Wpk2l = (unsigned short*)(ws + alloc(4096 * 8 * 2));
    int*   c2s    = (int*)(ws + alloc((size_t)n * 8 * 4));        // 0.64 MB
    int*   p2s    = (int*)(ws + alloc((size_t)n * 8 * CAP2S * 4)); // 5.12 MB

    int totalT = 4608 + 262144 + n;
    setup_kernel<<<(totalT + 255) / 256, 256, 0, stream>>>(
        W1, W2, coords, grid1, Wpk1h, Wpk1l, Wpk2h, Wpk2l, W2e, n);

    conv1_fused_kernel<<<nblk, 512, 0, stream>>>(coords, feats, W1, Wpk1h,
                                                 Wpk1l, b1, grid1, c2s, p2s, h,
                                                 n);
    conv2_fused_kernel<<<dim3(nblk, 4), 512, 0, stream>>>(
        h, Wpk2h, Wpk2l, W2e, b2, c2s, p2s, out, n);
}

// Round 21
// 79.533 us; speedup vs baseline: 1.1216x; 1.1216x over previous
//
#include <hip/hip_runtime.h>

#define D1 96
#define GRID_VOX (D1 * D1 * D1)
#define CAP2S 8   // per-(voxel,s) conv2 pairs (max 7 exact)
#define OS 68     // oT row stride in floats (bank-conflict pad, 16B aligned)

typedef __attribute__((ext_vector_type(8))) short short8_t;  // 8 bf16
typedef __attribute__((ext_vector_type(4))) float f32x4;

__device__ __forceinline__ unsigned short bf16rne(float x) {
    unsigned u = __float_as_uint(x);
    return (unsigned short)((u + 0x7FFF + ((u >> 16) & 1)) >> 16);
}
__device__ __forceinline__ void split2(float v, unsigned short& hi,
                                       unsigned short& lo) {
    hi = bf16rne(v);
    float hf = __uint_as_float((unsigned)hi << 16);
    lo = bf16rne(v - hf);
}
__device__ __forceinline__ float silu(float v) {
    return v / (1.f + __expf(-v));
}

// ---------------------------------------------------------------------------
// setupA (small, on critical path): Wpk1 pack [0,512) + grid scatter.
// No zero-fill needed: readers validate grid entries via exact coords match.
// ---------------------------------------------------------------------------
__global__ void setupA_kernel(const float* __restrict__ W1,
                              const int* __restrict__ coords,
                              unsigned short* __restrict__ grid,
                              unsigned short* __restrict__ Wpk1h,
                              unsigned short* __restrict__ Wpk1l, int n) {
    int t = blockIdx.x * blockDim.x + threadIdx.x;
    if (t < 512) {  // conv1 B-fragments: W1[13] self tap
        int fid = t >> 6, l = t & 63;
        int kb = fid >> 2, c = fid & 3;
#pragma unroll
        for (int e = 0; e < 8; ++e) {
            int ci = kb * 32 + ((l >> 4) << 3) + e;
            int co = c * 16 + (l & 15);
            unsigned short hi, lo;
            split2(W1[13 * 4096 + ci * 64 + co], hi, lo);
            Wpk1h[(size_t)t * 8 + e] = hi;
            Wpk1l[(size_t)t * 8 + e] = lo;
        }
    } else {  // scatter
        int i = t - 512;
        if (i < n)
            grid[(coords[3 * i] * D1 + coords[3 * i + 1]) * D1 +
                 coords[3 * i + 2]] = (unsigned short)(i + 1);
    }
}

// ---------------------------------------------------------------------------
__device__ __forceinline__ void load_split_A(const float* __restrict__ src,
                                             int arow, int lane, short8_t& ah0,
                                             short8_t& al0, short8_t& ah1,
                                             short8_t& al1) {
    const float* ap = src + (size_t)arow * 64 + ((lane >> 4) << 3);
    f32x4 a0 = *(const f32x4*)(ap);
    f32x4 a1 = *(const f32x4*)(ap + 4);
    f32x4 a2 = *(const f32x4*)(ap + 32);
    f32x4 a3 = *(const f32x4*)(ap + 36);
#pragma unroll
    for (int e = 0; e < 4; ++e) {
        unsigned short hh, ll;
        split2(a0[e], hh, ll); ah0[e] = (short)hh; al0[e] = (short)ll;
        split2(a1[e], hh, ll); ah0[4 + e] = (short)hh; al0[4 + e] = (short)ll;
        split2(a2[e], hh, ll); ah1[e] = (short)hh; al1[e] = (short)ll;
        split2(a3[e], hh, ll); ah1[4 + e] = (short)hh; al1[4 + e] = (short)ll;
    }
}

// ---------------------------------------------------------------------------
// 8-wave dense: wave w covers rows [(w&3)*16, +16) x col-tiles {2*(w>>2), +1}.
// ---------------------------------------------------------------------------
__device__ __forceinline__ void dense_mfma8(const short8_t ah0, const short8_t al0,
                                            const short8_t ah1, const short8_t al1,
                                            const short8_t* __restrict__ Bh,
                                            const short8_t* __restrict__ Bl,
                                            const float* __restrict__ bias,
                                            float* __restrict__ oT, int w,
                                            int lane) {
    int c0 = (w >> 2) * 2;
#pragma unroll
    for (int cc = 0; cc < 2; ++cc) {
        int c = c0 + cc;
        short8_t bh0 = Bh[c * 64 + lane];
        short8_t bl0 = Bl[c * 64 + lane];
        short8_t bh1 = Bh[(4 + c) * 64 + lane];
        short8_t bl1 = Bl[(4 + c) * 64 + lane];
        f32x4 acc = {0.f, 0.f, 0.f, 0.f};
        acc = __builtin_amdgcn_mfma_f32_16x16x32_bf16(ah0, bh0, acc, 0, 0, 0);
        acc = __builtin_amdgcn_mfma_f32_16x16x32_bf16(al0, bh0, acc, 0, 0, 0);
        acc = __builtin_amdgcn_mfma_f32_16x16x32_bf16(ah0, bl0, acc, 0, 0, 0);
        acc = __builtin_amdgcn_mfma_f32_16x16x32_bf16(ah1, bh1, acc, 0, 0, 0);
        acc = __builtin_amdgcn_mfma_f32_16x16x32_bf16(al1, bh1, acc, 0, 0, 0);
        acc = __builtin_amdgcn_mfma_f32_16x16x32_bf16(ah1, bl1, acc, 0, 0, 0);
        int col = c * 16 + (lane & 15);
        float bb = bias[col];
#pragma unroll
        for (int r = 0; r < 4; ++r) {
            int row = (w & 3) * 16 + ((lane >> 4) << 2) + r;
            oT[row * OS + col] = acc[r] + bb;
        }
    }
}

// wave-scan helper (wave 0): counts -> excl prefix + total, stored in LDS
__device__ __forceinline__ void scan64(int cnt, int lane, int* pfxs, int* cnts,
                                       int* nps) {
    int val = cnt;
#pragma unroll
    for (int off = 1; off < 64; off <<= 1) {
        int v2 = __shfl_up(val, off);
        if (lane >= off) val += v2;
    }
    pfxs[lane] = val - cnt;
    cnts[lane] = cnt;
    if (lane == 63) nps[0] = val;
}

// ---------------------------------------------------------------------------
// Barrier-free per-wave fixup loop (8 waves, stride 8; oT stride OS).
// ---------------------------------------------------------------------------
__device__ __forceinline__ void fixup_loop(const float* __restrict__ src,
                                           const float* __restrict__ Wbase,
                                           const int* __restrict__ pl, int np,
                                           float fsc[8][2][64],
                                           float* __restrict__ oT, int w,
                                           int lane) {
    int it = 0;
#pragma unroll 1
    for (int p = w; p < np; p += 8, ++it) {
        int e = pl[p];
        int j = e & 0x1FFFF, tag = (e >> 17) & 31, row = (e >> 23) & 63;
        float fv = src[(size_t)j * 64 + lane];  // coalesced 256B row
        int buf = it & 1;
        fsc[w][buf][lane] = fv;
        const float* wk = Wbase + (size_t)tag * 4096;  // [ci][co]
        float a0 = 0.f, a1 = 0.f, a2 = 0.f, a3 = 0.f;
#pragma unroll
        for (int c4 = 0; c4 < 16; ++c4) {
            f32x4 fb = *(f32x4*)&fsc[w][buf][c4 * 4];  // ds broadcast
            a0 += fb[0] * wk[(c4 * 4 + 0) * 64 + lane];
            a1 += fb[1] * wk[(c4 * 4 + 1) * 64 + lane];
            a2 += fb[2] * wk[(c4 * 4 + 2) * 64 + lane];
            a3 += fb[3] * wk[(c4 * 4 + 3) * 64 + lane];
        }
        atomicAdd(&oT[row * OS + lane], (a0 + a1) + (a2 + a3));
    }
}

// ---------------------------------------------------------------------------
// conv1 fused + hidden conv2-weight prep. Blocks [0,nblk): round-18 conv1
// (inline pair build, dense MFMA, fixups, SiLU). Blocks [nblk, nblk+520):
// pack Wpk2 fragments + fold W2e — consumed only by conv2 (next launch), so
// they run in conv1's shadow and exit before any barrier.
// ---------------------------------------------------------------------------
__global__ __launch_bounds__(512) void conv1_fused_kernel(
    const int* __restrict__ coords, const float* __restrict__ feats,
    const float* __restrict__ W1, const float* __restrict__ W2,
    const unsigned short* __restrict__ Wpk1h,
    const unsigned short* __restrict__ Wpk1l, const float* __restrict__ b1,
    const unsigned short* __restrict__ grid, int* __restrict__ c2s,
    int* __restrict__ p2s, unsigned short* __restrict__ Wpk2h,
    unsigned short* __restrict__ Wpk2l, float* __restrict__ W2e,
    float* __restrict__ h, int n, int nblk) {
    if (blockIdx.x >= nblk) {  // ---- prep-tail blocks (no LDS, no barriers)
        int t = (blockIdx.x - nblk) * 512 + threadIdx.x;
        if (t < 4096) {  // conv2 dense (self-parent fold) fragments
            int u = t;
            int fid = u >> 6, l = u & 63;
            int s = fid >> 3, kb = (fid >> 2) & 1, c = fid & 3;
            int s0 = (s >> 2) & 1, s1 = (s >> 1) & 1, s2 = s & 1;
#pragma unroll
            for (int e = 0; e < 8; ++e) {
                int ci = kb * 32 + ((l >> 4) << 3) + e;
                int co = c * 16 + (l & 15);
                float sum = 0.f;
                for (int o0 = -s0; o0 <= 1 - s0; ++o0)
                    for (int o1 = -s1; o1 <= 1 - s1; ++o1)
                        for (int o2 = -s2; o2 <= 1 - s2; ++o2) {
                            int k = (o0 + 1) * 9 + (o1 + 1) * 3 + (o2 + 1);
                            sum += W2[k * 4096 + ci * 64 + co];
                        }
                unsigned short hi, lo;
                split2(sum, hi, lo);
                Wpk2h[(size_t)u * 8 + e] = hi;
                Wpk2l[(size_t)u * 8 + e] = lo;
            }
        } else if (t < 4096 + 262144) {  // W2e fp32 fixup weights
            int r = t - 4096;
            int sd = r >> 12, e = r & 4095;
            int s = sd >> 3, d = sd & 7;
            int sa[3] = { (s >> 2) & 1, (s >> 1) & 1, s & 1 };
            int da[3] = { (d >> 2) & 1, (d >> 1) & 1, d & 1 };
            int lo_[3], hi_[3];
            for (int a = 0; a < 3; ++a) {
                int p = sa[a] - 1 + da[a];
                int l = 2 * p - sa[a];     if (l < -1) l = -1;
                int hh = 2 * p + 1 - sa[a]; if (hh > 1) hh = 1;
                lo_[a] = l; hi_[a] = hh;
            }
            float sum = 0.f;
            for (int o0 = lo_[0]; o0 <= hi_[0]; ++o0)
                for (int o1 = lo_[1]; o1 <= hi_[1]; ++o1)
                    for (int o2 = lo_[2]; o2 <= hi_[2]; ++o2) {
                        int k = (o0 + 1) * 9 + (o1 + 1) * 3 + (o2 + 1);
                        sum += W2[k * 4096 + e];
                    }
            W2e[(size_t)sd * 4096 + e] = sum;
        }
        return;
    }

    __shared__ __align__(16) float oT[64 * OS];
    __shared__ __align__(16) float fsc[8][2][64];
    __shared__ int plt[64 * 26];
    __shared__ int pl[1664];
    __shared__ int pfxs[64], cnts_s[64], nps[1];
    int base = blockIdx.x * 64;
    int t = threadIdx.x, w = t >> 6, lane = t & 63;

    if (t < 64) {  // inline pair build with validated grid reads
        int myv = base + t;
        int cnt = 0;
        if (myv < n) {
            int c0 = coords[3 * myv], c1v = coords[3 * myv + 1],
                c2v = coords[3 * myv + 2];
            int n2[8] = {0, 0, 0, 0, 0, 0, 0, 0};
#pragma unroll 1
            for (int g = 0; g < 3; ++g) {
                int jv9[9];
                int kb = g * 9;
#pragma unroll
                for (int u = 0; u < 9; ++u) {
                    int k = kb + u;
                    int o0 = k / 9 - 1, o1 = (k / 3) % 3 - 1, o2 = k % 3 - 1;
                    int x0 = c0 + o0, x1 = c1v + o1, x2 = c2v + o2;
                    bool inb = (unsigned)x0 < D1 && (unsigned)x1 < D1 &&
                               (unsigned)x2 < D1;
                    jv9[u] = inb ? (int)grid[(x0 * D1 + x1) * D1 + x2] : 0;
                }
#pragma unroll
                for (int u = 0; u < 9; ++u) {
                    int k = kb + u;
                    if (k == 13) continue;
                    int j1 = jv9[u];
                    if (j1 < 1 || j1 > n) continue;  // poison/garbage reject
                    int o0 = k / 9 - 1, o1 = (k / 3) % 3 - 1, o2 = k % 3 - 1;
                    int x0 = c0 + o0, x1 = c1v + o1, x2 = c2v + o2;
                    int jj = j1 - 1;
                    if (coords[3 * jj] != x0 || coords[3 * jj + 1] != x1 ||
                        coords[3 * jj + 2] != x2)
                        continue;
                    plt[t * 26 + cnt] = jj | (k << 17);
                    ++cnt;
#pragma unroll
                    for (int s = 0; s < 8; ++s) {
                        int d0 = o0 + 1 - ((s >> 2) & 1);
                        int d1 = o1 + 1 - ((s >> 1) & 1);
                        int d2 = o2 + 1 - (s & 1);
                        if (((d0 | d1 | d2) & ~1) == 0) {
                            int d = (d0 << 2) | (d1 << 1) | d2;
                            p2s[((size_t)myv * 8 + s) * CAP2S + n2[s]] =
                                jj | (d << 17);
                            ++n2[s];
                        }
                    }
                }
            }
#pragma unroll
            for (int s = 0; s < 8; ++s) c2s[myv * 8 + s] = n2[s];
        }
        scan64(cnt, lane, pfxs, cnts_s, nps);
    }

    int arow = base + (w & 3) * 16 + (lane & 15);
    if (arow >= n) arow = n - 1;
    short8_t ah0, al0, ah1, al1;
    load_split_A(feats, arow, lane, ah0, al0, ah1, al1);
    dense_mfma8(ah0, al0, ah1, al1, (const short8_t*)Wpk1h,
                (const short8_t*)Wpk1l, b1, oT, w, lane);
    __syncthreads();

    {   // parallel compaction: 8 threads per row
        int row = t & 63, e0 = t >> 6;
        int cr = cnts_s[row], pf = pfxs[row];
        for (int e = e0; e < cr; e += 8)
            pl[pf + e] = plt[row * 26 + e] | (row << 23);
    }
    __syncthreads();

    fixup_loop(feats, W1, pl, nps[0], fsc, oT, w, lane);
    __syncthreads();

    {   // SiLU + coalesced store
        int r = t >> 3, c8 = (t & 7) * 8;
        if (base + r < n) {
#pragma unroll
            for (int jj = 0; jj < 2; ++jj) {
                f32x4 v = *(f32x4*)&oT[r * OS + c8 + jj * 4];
#pragma unroll
                for (int u = 0; u < 4; ++u) v[u] = silu(v[u]);
                *(f32x4*)&h[(size_t)(base + r) * 64 + c8 + jj * 4] = v;
            }
        }
    }
}

// ---------------------------------------------------------------------------
// conv2 fused (round-19 best): 1D grid with XCD tile-affinity swizzle.
//   Tm = idx%8; s = (idx/8)%8; T = (idx/64)*8 + Tm
// ---------------------------------------------------------------------------
__global__ __launch_bounds__(512) void conv2_fused_kernel(
    const float* __restrict__ h, const unsigned short* __restrict__ Wpk2h,
    const unsigned short* __restrict__ Wpk2l, const float* __restrict__ W2e,
    const float* __restrict__ b2, const int* __restrict__ c2s,
    const int* __restrict__ p2s, float* __restrict__ out, int n) {
    __shared__ __align__(16) float oT[64 * OS];
    __shared__ __align__(16) float fsc[8][2][64];
    __shared__ int pl[448];
    __shared__ int pfxs[64], cnts_s[64], nps[1];
    int idx = blockIdx.x;
    int Tm = idx & 7, s = (idx >> 3) & 7, T = (idx >> 6) * 8 + Tm;
    int base = T * 64;
    if (base >= n) return;
    int t = threadIdx.x, w = t >> 6, lane = t & 63;

    if (t < 64) {
        int cnt = (base + lane < n) ? c2s[(size_t)(base + lane) * 8 + s] : 0;
        scan64(cnt, lane, pfxs, cnts_s, nps);
    }

    int arow = base + (w & 3) * 16 + (lane & 15);
    if (arow >= n) arow = n - 1;
    short8_t ah0, al0, ah1, al1;
    load_split_A(h, arow, lane, ah0, al0, ah1, al1);
    dense_mfma8(ah0, al0, ah1, al1,
                (const short8_t*)Wpk2h + (size_t)s * 8 * 64,
                (const short8_t*)Wpk2l + (size_t)s * 8 * 64, b2, oT, w, lane);
    __syncthreads();

    {   // parallel compaction: 8 threads per row
        int row = t & 63, e0 = t >> 6;
        int cr = cnts_s[row], pf = pfxs[row];
        for (int e = e0; e < cr; e += 8)
            pl[pf + e] =
                p2s[((size_t)(base + row) * 8 + s) * CAP2S + e] | (row << 23);
    }
    __syncthreads();

    fixup_loop(h, W2e + (size_t)s * 8 * 4096, pl, nps[0], fsc, oT, w, lane);
    __syncthreads();

    {   // SiLU + coalesced store (out row = parent*8 + s)
        int r = t >> 3, c8 = (t & 7) * 8;
        if (base + r < n) {
#pragma unroll
            for (int jj = 0; jj < 2; ++jj) {
                f32x4 v = *(f32x4*)&oT[r * OS + c8 + jj * 4];
#pragma unroll
                for (int u = 0; u < 4; ++u) v[u] = silu(v[u]);
                *(f32x4*)&out[((size_t)(base + r) * 8 + s) * 64 + c8 + jj * 4] = v;
            }
        }
    }
}

// ---------------------------------------------------------------------------
extern "C" void kernel_launch(void* const* d_in, const int* in_sizes, int n_in,
                              void* d_out, int out_size, void* d_ws,
                              size_t ws_size, hipStream_t stream) {
    const int* coords = (const int*)d_in[0];
    const float* feats = (const float*)d_in[1];
    const float* W1 = (const float*)d_in[2];
    const float* b1 = (const float*)d_in[3];
    const float* W2 = (const float*)d_in[4];
    const float* b2 = (const float*)d_in[5];
    float* out = (float*)d_out;

    int n = in_sizes[0] / 3;  // 20000
    int nblk = (n + 63) / 64; // 313

    char* ws = (char*)d_ws;
    size_t off = 0;
    auto alloc = [&](size_t bytes) {
        size_t o = off;
        off = (off + bytes + 255) & ~(size_t)255;
        return o;
    };
    unsigned short* grid1 = (unsigned short*)(ws + alloc((size_t)GRID_VOX * 2));
    float* h      = (float*)(ws + alloc((size_t)n * 64 * 4));     // 5.12 MB
    float* W2e    = (float*)(ws + alloc(64 * 4096 * 4));          // 1 MB
    unsigned short* Wpk1h = (unsigned short*)(ws + alloc(512 * 8 * 2));
    unsigned short* Wpk1l = (unsigned short*)(ws + alloc(512 * 8 * 2));
    unsigned short* Wpk2h = (unsigned short*)(ws + alloc(4096 * 8 * 2));
    unsigned short* Wpk2l = (unsigned short*)(ws + alloc(4096 * 8 * 2));
    int*   c2s    = (int*)(ws + alloc((size_t)n * 8 * 4));        // 0.64 MB
    int*   p2s    = (int*)(ws + alloc((size_t)n * 8 * CAP2S * 4)); // 5.12 MB

    // setupA: Wpk1 pack + grid scatter only (small, fast)
    setupA_kernel<<<(512 + n + 255) / 256, 256, 0, stream>>>(
        W1, coords, grid1, Wpk1h, Wpk1l, n);

    // conv1 + hidden conv2-weight prep (520 tail blocks)
    int prepBlocks = (4096 + 262144 + 511) / 512;  // 520
    conv1_fused_kernel<<<nblk + prepBlocks, 512, 0, stream>>>(
        coords, feats, W1, W2, Wpk1h, Wpk1l, b1, grid1, c2s, p2s, Wpk2h,
        Wpk2l, W2e, h, n, nblk);

    int nTileGrp = (nblk + 7) / 8;  // 40
    conv2_fused_kernel<<<nTileGrp * 64, 512, 0, stream>>>(
        h, Wpk2h, Wpk2l, W2e, b2, c2s, p2s, out, n);
}

// Round 22
// 74.407 us; speedup vs baseline: 1.1988x; 1.0689x over previous
//
#include <hip/hip_runtime.h>

#define D1 96
#define GRID_VOX (D1 * D1 * D1)
#define CAP2S 8   // per-(voxel,s) conv2 pairs (max 7 exact)
#define OS 68     // oT row stride in floats (bank-conflict pad, 16B aligned)

typedef __attribute__((ext_vector_type(8))) short short8_t;  // 8 bf16
typedef __attribute__((ext_vector_type(4))) float f32x4;

__device__ __forceinline__ unsigned short bf16rne(float x) {
    unsigned u = __float_as_uint(x);
    return (unsigned short)((u + 0x7FFF + ((u >> 16) & 1)) >> 16);
}
__device__ __forceinline__ void split2(float v, unsigned short& hi,
                                       unsigned short& lo) {
    hi = bf16rne(v);
    float hf = __uint_as_float((unsigned)hi << 16);
    lo = bf16rne(v - hf);
}
__device__ __forceinline__ float silu(float v) {
    return v / (1.f + __expf(-v));
}

// ---------------------------------------------------------------------------
// setupA (small, on critical path): Wpk1 pack [0,512) + grid scatter.
// No zero-fill needed: readers validate grid entries via exact coords match.
// ---------------------------------------------------------------------------
__global__ void setupA_kernel(const float* __restrict__ W1,
                              const int* __restrict__ coords,
                              unsigned short* __restrict__ grid,
                              unsigned short* __restrict__ Wpk1h,
                              unsigned short* __restrict__ Wpk1l, int n) {
    int t = blockIdx.x * blockDim.x + threadIdx.x;
    if (t < 512) {  // conv1 B-fragments: W1[13] self tap
        int fid = t >> 6, l = t & 63;
        int kb = fid >> 2, c = fid & 3;
#pragma unroll
        for (int e = 0; e < 8; ++e) {
            int ci = kb * 32 + ((l >> 4) << 3) + e;
            int co = c * 16 + (l & 15);
            unsigned short hi, lo;
            split2(W1[13 * 4096 + ci * 64 + co], hi, lo);
            Wpk1h[(size_t)t * 8 + e] = hi;
            Wpk1l[(size_t)t * 8 + e] = lo;
        }
    } else {  // scatter
        int i = t - 512;
        if (i < n)
            grid[(coords[3 * i] * D1 + coords[3 * i + 1]) * D1 +
                 coords[3 * i + 2]] = (unsigned short)(i + 1);
    }
}

// ---------------------------------------------------------------------------
__device__ __forceinline__ void load_split_A(const float* __restrict__ src,
                                             int arow, int lane, short8_t& ah0,
                                             short8_t& al0, short8_t& ah1,
                                             short8_t& al1) {
    const float* ap = src + (size_t)arow * 64 + ((lane >> 4) << 3);
    f32x4 a0 = *(const f32x4*)(ap);
    f32x4 a1 = *(const f32x4*)(ap + 4);
    f32x4 a2 = *(const f32x4*)(ap + 32);
    f32x4 a3 = *(const f32x4*)(ap + 36);
#pragma unroll
    for (int e = 0; e < 4; ++e) {
        unsigned short hh, ll;
        split2(a0[e], hh, ll); ah0[e] = (short)hh; al0[e] = (short)ll;
        split2(a1[e], hh, ll); ah0[4 + e] = (short)hh; al0[4 + e] = (short)ll;
        split2(a2[e], hh, ll); ah1[e] = (short)hh; al1[e] = (short)ll;
        split2(a3[e], hh, ll); ah1[4 + e] = (short)hh; al1[4 + e] = (short)ll;
    }
}

// ---------------------------------------------------------------------------
// conv1 dense (32-row tile): wave w -> row-group (w&1), col-tile (w>>1).
// 6 MFMAs per wave, one 16x16 output tile.
// ---------------------------------------------------------------------------
__device__ __forceinline__ void dense_mfma32(const short8_t ah0, const short8_t al0,
                                             const short8_t ah1, const short8_t al1,
                                             const short8_t* __restrict__ Bh,
                                             const short8_t* __restrict__ Bl,
                                             const float* __restrict__ bias,
                                             float* __restrict__ oT, int w,
                                             int lane) {
    int c = w >> 1;
    short8_t bh0 = Bh[c * 64 + lane];
    short8_t bl0 = Bl[c * 64 + lane];
    short8_t bh1 = Bh[(4 + c) * 64 + lane];
    short8_t bl1 = Bl[(4 + c) * 64 + lane];
    f32x4 acc = {0.f, 0.f, 0.f, 0.f};
    acc = __builtin_amdgcn_mfma_f32_16x16x32_bf16(ah0, bh0, acc, 0, 0, 0);
    acc = __builtin_amdgcn_mfma_f32_16x16x32_bf16(al0, bh0, acc, 0, 0, 0);
    acc = __builtin_amdgcn_mfma_f32_16x16x32_bf16(ah0, bl0, acc, 0, 0, 0);
    acc = __builtin_amdgcn_mfma_f32_16x16x32_bf16(ah1, bh1, acc, 0, 0, 0);
    acc = __builtin_amdgcn_mfma_f32_16x16x32_bf16(al1, bh1, acc, 0, 0, 0);
    acc = __builtin_amdgcn_mfma_f32_16x16x32_bf16(ah1, bl1, acc, 0, 0, 0);
    int col = c * 16 + (lane & 15);
    float bb = bias[col];
#pragma unroll
    for (int r = 0; r < 4; ++r) {
        int row = (w & 1) * 16 + ((lane >> 4) << 2) + r;
        oT[row * OS + col] = acc[r] + bb;
    }
}

// 8-wave dense for conv2 (64-row tile): wave w -> rows (w&3)*16, col-tiles
// {2*(w>>2), +1}.
__device__ __forceinline__ void dense_mfma8(const short8_t ah0, const short8_t al0,
                                            const short8_t ah1, const short8_t al1,
                                            const short8_t* __restrict__ Bh,
                                            const short8_t* __restrict__ Bl,
                                            const float* __restrict__ bias,
                                            float* __restrict__ oT, int w,
                                            int lane) {
    int c0 = (w >> 2) * 2;
#pragma unroll
    for (int cc = 0; cc < 2; ++cc) {
        int c = c0 + cc;
        short8_t bh0 = Bh[c * 64 + lane];
        short8_t bl0 = Bl[c * 64 + lane];
        short8_t bh1 = Bh[(4 + c) * 64 + lane];
        short8_t bl1 = Bl[(4 + c) * 64 + lane];
        f32x4 acc = {0.f, 0.f, 0.f, 0.f};
        acc = __builtin_amdgcn_mfma_f32_16x16x32_bf16(ah0, bh0, acc, 0, 0, 0);
        acc = __builtin_amdgcn_mfma_f32_16x16x32_bf16(al0, bh0, acc, 0, 0, 0);
        acc = __builtin_amdgcn_mfma_f32_16x16x32_bf16(ah0, bl0, acc, 0, 0, 0);
        acc = __builtin_amdgcn_mfma_f32_16x16x32_bf16(ah1, bh1, acc, 0, 0, 0);
        acc = __builtin_amdgcn_mfma_f32_16x16x32_bf16(al1, bh1, acc, 0, 0, 0);
        acc = __builtin_amdgcn_mfma_f32_16x16x32_bf16(ah1, bl1, acc, 0, 0, 0);
        int col = c * 16 + (lane & 15);
        float bb = bias[col];
#pragma unroll
        for (int r = 0; r < 4; ++r) {
            int row = (w & 3) * 16 + ((lane >> 4) << 2) + r;
            oT[row * OS + col] = acc[r] + bb;
        }
    }
}

// wave-scan helper (wave 0): counts -> excl prefix + total, stored in LDS
__device__ __forceinline__ void scan64(int cnt, int lane, int* pfxs, int* cnts,
                                       int* nps) {
    int val = cnt;
#pragma unroll
    for (int off = 1; off < 64; off <<= 1) {
        int v2 = __shfl_up(val, off);
        if (lane >= off) val += v2;
    }
    pfxs[lane] = val - cnt;
    cnts[lane] = cnt;
    if (lane == 63) nps[0] = val;
}

// ---------------------------------------------------------------------------
// Barrier-free per-wave fixup loop (8 waves, stride 8; oT stride OS).
// ---------------------------------------------------------------------------
__device__ __forceinline__ void fixup_loop(const float* __restrict__ src,
                                           const float* __restrict__ Wbase,
                                           const int* __restrict__ pl, int np,
                                           float fsc[8][2][64],
                                           float* __restrict__ oT, int w,
                                           int lane) {
    int it = 0;
#pragma unroll 1
    for (int p = w; p < np; p += 8, ++it) {
        int e = pl[p];
        int j = e & 0x1FFFF, tag = (e >> 17) & 31, row = (e >> 23) & 63;
        float fv = src[(size_t)j * 64 + lane];  // coalesced 256B row
        int buf = it & 1;
        fsc[w][buf][lane] = fv;
        const float* wk = Wbase + (size_t)tag * 4096;  // [ci][co]
        float a0 = 0.f, a1 = 0.f, a2 = 0.f, a3 = 0.f;
#pragma unroll
        for (int c4 = 0; c4 < 16; ++c4) {
            f32x4 fb = *(f32x4*)&fsc[w][buf][c4 * 4];  // ds broadcast
            a0 += fb[0] * wk[(c4 * 4 + 0) * 64 + lane];
            a1 += fb[1] * wk[(c4 * 4 + 1) * 64 + lane];
            a2 += fb[2] * wk[(c4 * 4 + 2) * 64 + lane];
            a3 += fb[3] * wk[(c4 * 4 + 3) * 64 + lane];
        }
        atomicAdd(&oT[row * OS + lane], (a0 + a1) + (a2 + a3));
    }
}

// ---------------------------------------------------------------------------
// conv1 fused (32-row tiles) + hidden conv2-weight prep tail.
// Blocks [0,nblk1): build (threads 0..31, one row each) -> dense -> fixups
// -> SiLU. Blocks [nblk1, nblk1+520): pack Wpk2 + fold W2e, exit.
// ---------------------------------------------------------------------------
__global__ __launch_bounds__(512) void conv1_fused_kernel(
    const int* __restrict__ coords, const float* __restrict__ feats,
    const float* __restrict__ W1, const float* __restrict__ W2,
    const unsigned short* __restrict__ Wpk1h,
    const unsigned short* __restrict__ Wpk1l, const float* __restrict__ b1,
    const unsigned short* __restrict__ grid, int* __restrict__ c2s,
    int* __restrict__ p2s, unsigned short* __restrict__ Wpk2h,
    unsigned short* __restrict__ Wpk2l, float* __restrict__ W2e,
    float* __restrict__ h, int n, int nblk1) {
    if (blockIdx.x >= nblk1) {  // ---- prep-tail blocks (no LDS, no barriers)
        int t = (blockIdx.x - nblk1) * 512 + threadIdx.x;
        if (t < 4096) {  // conv2 dense (self-parent fold) fragments
            int u = t;
            int fid = u >> 6, l = u & 63;
            int s = fid >> 3, kb = (fid >> 2) & 1, c = fid & 3;
            int s0 = (s >> 2) & 1, s1 = (s >> 1) & 1, s2 = s & 1;
#pragma unroll
            for (int e = 0; e < 8; ++e) {
                int ci = kb * 32 + ((l >> 4) << 3) + e;
                int co = c * 16 + (l & 15);
                float sum = 0.f;
                for (int o0 = -s0; o0 <= 1 - s0; ++o0)
                    for (int o1 = -s1; o1 <= 1 - s1; ++o1)
                        for (int o2 = -s2; o2 <= 1 - s2; ++o2) {
                            int k = (o0 + 1) * 9 + (o1 + 1) * 3 + (o2 + 1);
                            sum += W2[k * 4096 + ci * 64 + co];
                        }
                unsigned short hi, lo;
                split2(sum, hi, lo);
                Wpk2h[(size_t)u * 8 + e] = hi;
                Wpk2l[(size_t)u * 8 + e] = lo;
            }
        } else if (t < 4096 + 262144) {  // W2e fp32 fixup weights
            int r = t - 4096;
            int sd = r >> 12, e = r & 4095;
            int s = sd >> 3, d = sd & 7;
            int sa[3] = { (s >> 2) & 1, (s >> 1) & 1, s & 1 };
            int da[3] = { (d >> 2) & 1, (d >> 1) & 1, d & 1 };
            int lo_[3], hi_[3];
            for (int a = 0; a < 3; ++a) {
                int p = sa[a] - 1 + da[a];
                int l = 2 * p - sa[a];     if (l < -1) l = -1;
                int hh = 2 * p + 1 - sa[a]; if (hh > 1) hh = 1;
                lo_[a] = l; hi_[a] = hh;
            }
            float sum = 0.f;
            for (int o0 = lo_[0]; o0 <= hi_[0]; ++o0)
                for (int o1 = lo_[1]; o1 <= hi_[1]; ++o1)
                    for (int o2 = lo_[2]; o2 <= hi_[2]; ++o2) {
                        int k = (o0 + 1) * 9 + (o1 + 1) * 3 + (o2 + 1);
                        sum += W2[k * 4096 + e];
                    }
            W2e[(size_t)sd * 4096 + e] = sum;
        }
        return;
    }

    __shared__ __align__(16) float oT[32 * OS];
    __shared__ __align__(16) float fsc[8][2][64];
    __shared__ int plt[32 * 26];
    __shared__ int pl[832];
    __shared__ int pfxs[64], cnts_s[64], nps[1];
    int base = blockIdx.x * 32;
    int t = threadIdx.x, w = t >> 6, lane = t & 63;

    if (t < 64) {  // build: threads 0..31 (one row each); all of wave 0 scans
        int cnt = 0;
        if (t < 32) {
            int myv = base + t;
            if (myv < n) {
                int c0 = coords[3 * myv], c1v = coords[3 * myv + 1],
                    c2v = coords[3 * myv + 2];
                int n2[8] = {0, 0, 0, 0, 0, 0, 0, 0};
#pragma unroll 1
                for (int g = 0; g < 3; ++g) {
                    int jv9[9];
                    int kb = g * 9;
#pragma unroll
                    for (int u = 0; u < 9; ++u) {
                        int k = kb + u;
                        int o0 = k / 9 - 1, o1 = (k / 3) % 3 - 1,
                            o2 = k % 3 - 1;
                        int x0 = c0 + o0, x1 = c1v + o1, x2 = c2v + o2;
                        bool inb = (unsigned)x0 < D1 && (unsigned)x1 < D1 &&
                                   (unsigned)x2 < D1;
                        jv9[u] = inb ? (int)grid[(x0 * D1 + x1) * D1 + x2] : 0;
                    }
#pragma unroll
                    for (int u = 0; u < 9; ++u) {
                        int k = kb + u;
                        if (k == 13) continue;
                        int j1 = jv9[u];
                        if (j1 < 1 || j1 > n) continue;  // poison reject
                        int o0 = k / 9 - 1, o1 = (k / 3) % 3 - 1,
                            o2 = k % 3 - 1;
                        int x0 = c0 + o0, x1 = c1v + o1, x2 = c2v + o2;
                        int jj = j1 - 1;
                        if (coords[3 * jj] != x0 ||
                            coords[3 * jj + 1] != x1 ||
                            coords[3 * jj + 2] != x2)
                            continue;
                        plt[t * 26 + cnt] = jj | (k << 17);
                        ++cnt;
#pragma unroll
                        for (int s = 0; s < 8; ++s) {
                            int d0 = o0 + 1 - ((s >> 2) & 1);
                            int d1 = o1 + 1 - ((s >> 1) & 1);
                            int d2 = o2 + 1 - (s & 1);
                            if (((d0 | d1 | d2) & ~1) == 0) {
                                int d = (d0 << 2) | (d1 << 1) | d2;
                                p2s[((size_t)myv * 8 + s) * CAP2S + n2[s]] =
                                    jj | (d << 17);
                                ++n2[s];
                            }
                        }
                    }
                }
#pragma unroll
                for (int s = 0; s < 8; ++s) c2s[myv * 8 + s] = n2[s];
            }
        }
        scan64(cnt, lane, pfxs, cnts_s, nps);
    }

    int arow = base + (w & 1) * 16 + (lane & 15);
    if (arow >= n) arow = n - 1;
    short8_t ah0, al0, ah1, al1;
    load_split_A(feats, arow, lane, ah0, al0, ah1, al1);
    dense_mfma32(ah0, al0, ah1, al1, (const short8_t*)Wpk1h,
                 (const short8_t*)Wpk1l, b1, oT, w, lane);
    __syncthreads();

    {   // parallel compaction: 16 threads per row (32 rows)
        int row = t & 31, e0 = t >> 5;
        int cr = cnts_s[row], pf = pfxs[row];
        for (int e = e0; e < cr; e += 16)
            pl[pf + e] = plt[row * 26 + e] | (row << 23);
    }
    __syncthreads();

    fixup_loop(feats, W1, pl, nps[0], fsc, oT, w, lane);
    __syncthreads();

    {   // SiLU + coalesced store: 512 threads, 4 floats each over 32x64
        int r = t >> 4, c4 = (t & 15) * 4;
        if (base + r < n) {
            f32x4 v = *(f32x4*)&oT[r * OS + c4];
#pragma unroll
            for (int u = 0; u < 4; ++u) v[u] = silu(v[u]);
            *(f32x4*)&h[(size_t)(base + r) * 64 + c4] = v;
        }
    }
}

// ---------------------------------------------------------------------------
// conv2 fused (round-19/21 best): 1D grid with XCD tile-affinity swizzle.
//   Tm = idx%8; s = (idx/8)%8; T = (idx/64)*8 + Tm
// ---------------------------------------------------------------------------
__global__ __launch_bounds__(512) void conv2_fused_kernel(
    const float* __restrict__ h, const unsigned short* __restrict__ Wpk2h,
    const unsigned short* __restrict__ Wpk2l, const float* __restrict__ W2e,
    const float* __restrict__ b2, const int* __restrict__ c2s,
    const int* __restrict__ p2s, float* __restrict__ out, int n) {
    __shared__ __align__(16) float oT[64 * OS];
    __shared__ __align__(16) float fsc[8][2][64];
    __shared__ int pl[448];
    __shared__ int pfxs[64], cnts_s[64], nps[1];
    int idx = blockIdx.x;
    int Tm = idx & 7, s = (idx >> 3) & 7, T = (idx >> 6) * 8 + Tm;
    int base = T * 64;
    if (base >= n) return;
    int t = threadIdx.x, w = t >> 6, lane = t & 63;

    if (t < 64) {
        int cnt = (base + lane < n) ? c2s[(size_t)(base + lane) * 8 + s] : 0;
        scan64(cnt, lane, pfxs, cnts_s, nps);
    }

    int arow = base + (w & 3) * 16 + (lane & 15);
    if (arow >= n) arow = n - 1;
    short8_t ah0, al0, ah1, al1;
    load_split_A(h, arow, lane, ah0, al0, ah1, al1);
    dense_mfma8(ah0, al0, ah1, al1,
                (const short8_t*)Wpk2h + (size_t)s * 8 * 64,
                (const short8_t*)Wpk2l + (size_t)s * 8 * 64, b2, oT, w, lane);
    __syncthreads();

    {   // parallel compaction: 8 threads per row
        int row = t & 63, e0 = t >> 6;
        int cr = cnts_s[row], pf = pfxs[row];
        for (int e = e0; e < cr; e += 8)
            pl[pf + e] =
                p2s[((size_t)(base + row) * 8 + s) * CAP2S + e] | (row << 23);
    }
    __syncthreads();

    fixup_loop(h, W2e + (size_t)s * 8 * 4096, pl, nps[0], fsc, oT, w, lane);
    __syncthreads();

    {   // SiLU + coalesced store (out row = parent*8 + s)
        int r = t >> 3, c8 = (t & 7) * 8;
        if (base + r < n) {
#pragma unroll
            for (int jj = 0; jj < 2; ++jj) {
                f32x4 v = *(f32x4*)&oT[r * OS + c8 + jj * 4];
#pragma unroll
                for (int u = 0; u < 4; ++u) v[u] = silu(v[u]);
                *(f32x4*)&out[((size_t)(base + r) * 8 + s) * 64 + c8 + jj * 4] = v;
            }
        }
    }
}

// ---------------------------------------------------------------------------
extern "C" void kernel_launch(void* const* d_in, const int* in_sizes, int n_in,
                              void* d_out, int out_size, void* d_ws,
                              size_t ws_size, hipStream_t stream) {
    const int* coords = (const int*)d_in[0];
    const float* feats = (const float*)d_in[1];
    const float* W1 = (const float*)d_in[2];
    const float* b1 = (const float*)d_in[3];
    const float* W2 = (const float*)d_in[4];
    const float* b2 = (const float*)d_in[5];
    float* out = (float*)d_out;

    int n = in_sizes[0] / 3;   // 20000
    int nblk = (n + 63) / 64;  // 313 (conv2 tiles)
    int nblk1 = (n + 31) / 32; // 625 (conv1 tiles)

    char* ws = (char*)d_ws;
    size_t off = 0;
    auto alloc = [&](size_t bytes) {
        size_t o = off;
        off = (off + bytes + 255) & ~(size_t)255;
        return o;
    };
    unsigned short* grid1 = (unsigned short*)(ws + alloc((size_t)GRID_VOX * 2));
    float* h      = (float*)(ws + alloc((size_t)n * 64 * 4));     // 5.12 MB
    float* W2e    = (float*)(ws + alloc(64 * 4096 * 4));          // 1 MB
    unsigned short* Wpk1h = (unsigned short*)(ws + alloc(512 * 8 * 2));
    unsigned short* Wpk1l = (unsigned short*)(ws + alloc(512 * 8 * 2));
    unsigned short* Wpk2h = (unsigned short*)(ws + alloc(4096 * 8 * 2));
    unsigned short* Wpk2l = (unsigned short*)(ws + alloc(4096 * 8 * 2));
    int*   c2s    = (int*)(ws + alloc((size_t)n * 8 * 4));        // 0.64 MB
    int*   p2s    = (int*)(ws + alloc((size_t)n * 8 * CAP2S * 4)); // 5.12 MB

    // setupA: Wpk1 pack + grid scatter only (small, fast)
    setupA_kernel<<<(512 + n + 255) / 256, 256, 0, stream>>>(
        W1, coords, grid1, Wpk1h, Wpk1l, n);

    // conv1 (32-row tiles) + hidden conv2-weight prep (520 tail blocks)
    int prepBlocks = (4096 + 262144 + 511) / 512;  // 520
    conv1_fused_kernel<<<nblk1 + prepBlocks, 512, 0, stream>>>(
        coords, feats, W1, W2, Wpk1h, Wpk1l, b1, grid1, c2s, p2s, Wpk2h,
        Wpk2l, W2e, h, n, nblk1);

    int nTileGrp = (nblk + 7) / 8;  // 40
    conv2_fused_kernel<<<nTileGrp * 64, 512, 0, stream>>>(
        h, Wpk2h, Wpk2l, W2e, b2, c2s, p2s, out, n);
}

// Round 23
// 73.478 us; speedup vs baseline: 1.2140x; 1.0126x over previous
//
#include <hip/hip_runtime.h>

#define D1 96
#define GRID_VOX (D1 * D1 * D1)
#define CAP2S 8   // per-(voxel,s) conv2 pairs (max 7 exact)
#define OS 68     // oT row stride in floats (bank-conflict pad, 16B aligned)

typedef __attribute__((ext_vector_type(8))) short short8_t;  // 8 bf16
typedef __attribute__((ext_vector_type(4))) float f32x4;

__device__ __forceinline__ unsigned short bf16rne(float x) {
    unsigned u = __float_as_uint(x);
    return (unsigned short)((u + 0x7FFF + ((u >> 16) & 1)) >> 16);
}
__device__ __forceinline__ void split2(float v, unsigned short& hi,
                                       unsigned short& lo) {
    hi = bf16rne(v);
    float hf = __uint_as_float((unsigned)hi << 16);
    lo = bf16rne(v - hf);
}
__device__ __forceinline__ float silu(float v) {
    return v / (1.f + __expf(-v));
}

// ---------------------------------------------------------------------------
// setupA (small, on critical path): Wpk1 pack [0,512) + grid scatter.
// No zero-fill needed: readers validate grid entries via exact coords match.
// ---------------------------------------------------------------------------
__global__ void setupA_kernel(const float* __restrict__ W1,
                              const int* __restrict__ coords,
                              unsigned short* __restrict__ grid,
                              unsigned short* __restrict__ Wpk1h,
                              unsigned short* __restrict__ Wpk1l, int n) {
    int t = blockIdx.x * blockDim.x + threadIdx.x;
    if (t < 512) {  // conv1 B-fragments: W1[13] self tap
        int fid = t >> 6, l = t & 63;
        int kb = fid >> 2, c = fid & 3;
#pragma unroll
        for (int e = 0; e < 8; ++e) {
            int ci = kb * 32 + ((l >> 4) << 3) + e;
            int co = c * 16 + (l & 15);
            unsigned short hi, lo;
            split2(W1[13 * 4096 + ci * 64 + co], hi, lo);
            Wpk1h[(size_t)t * 8 + e] = hi;
            Wpk1l[(size_t)t * 8 + e] = lo;
        }
    } else {  // scatter
        int i = t - 512;
        if (i < n)
            grid[(coords[3 * i] * D1 + coords[3 * i + 1]) * D1 +
                 coords[3 * i + 2]] = (unsigned short)(i + 1);
    }
}

// ---------------------------------------------------------------------------
__device__ __forceinline__ void load_split_A(const float* __restrict__ src,
                                             int arow, int lane, short8_t& ah0,
                                             short8_t& al0, short8_t& ah1,
                                             short8_t& al1) {
    const float* ap = src + (size_t)arow * 64 + ((lane >> 4) << 3);
    f32x4 a0 = *(const f32x4*)(ap);
    f32x4 a1 = *(const f32x4*)(ap + 4);
    f32x4 a2 = *(const f32x4*)(ap + 32);
    f32x4 a3 = *(const f32x4*)(ap + 36);
#pragma unroll
    for (int e = 0; e < 4; ++e) {
        unsigned short hh, ll;
        split2(a0[e], hh, ll); ah0[e] = (short)hh; al0[e] = (short)ll;
        split2(a1[e], hh, ll); ah0[4 + e] = (short)hh; al0[4 + e] = (short)ll;
        split2(a2[e], hh, ll); ah1[e] = (short)hh; al1[e] = (short)ll;
        split2(a3[e], hh, ll); ah1[4 + e] = (short)hh; al1[4 + e] = (short)ll;
    }
}

// ---------------------------------------------------------------------------
// conv1 dense (32-row tile): wave w -> row-group (w&1), col-tile (w>>1).
// ---------------------------------------------------------------------------
__device__ __forceinline__ void dense_mfma32(const short8_t ah0, const short8_t al0,
                                             const short8_t ah1, const short8_t al1,
                                             const short8_t* __restrict__ Bh,
                                             const short8_t* __restrict__ Bl,
                                             const float* __restrict__ bias,
                                             float* __restrict__ oT, int w,
                                             int lane) {
    int c = w >> 1;
    short8_t bh0 = Bh[c * 64 + lane];
    short8_t bl0 = Bl[c * 64 + lane];
    short8_t bh1 = Bh[(4 + c) * 64 + lane];
    short8_t bl1 = Bl[(4 + c) * 64 + lane];
    f32x4 acc = {0.f, 0.f, 0.f, 0.f};
    acc = __builtin_amdgcn_mfma_f32_16x16x32_bf16(ah0, bh0, acc, 0, 0, 0);
    acc = __builtin_amdgcn_mfma_f32_16x16x32_bf16(al0, bh0, acc, 0, 0, 0);
    acc = __builtin_amdgcn_mfma_f32_16x16x32_bf16(ah0, bl0, acc, 0, 0, 0);
    acc = __builtin_amdgcn_mfma_f32_16x16x32_bf16(ah1, bh1, acc, 0, 0, 0);
    acc = __builtin_amdgcn_mfma_f32_16x16x32_bf16(al1, bh1, acc, 0, 0, 0);
    acc = __builtin_amdgcn_mfma_f32_16x16x32_bf16(ah1, bl1, acc, 0, 0, 0);
    int col = c * 16 + (lane & 15);
    float bb = bias[col];
#pragma unroll
    for (int r = 0; r < 4; ++r) {
        int row = (w & 1) * 16 + ((lane >> 4) << 2) + r;
        oT[row * OS + col] = acc[r] + bb;
    }
}

// 8-wave dense for conv2 (64-row tile): wave w -> rows (w&3)*16, col-tiles
// {2*(w>>2), +1}.
__device__ __forceinline__ void dense_mfma8(const short8_t ah0, const short8_t al0,
                                            const short8_t ah1, const short8_t al1,
                                            const short8_t* __restrict__ Bh,
                                            const short8_t* __restrict__ Bl,
                                            const float* __restrict__ bias,
                                            float* __restrict__ oT, int w,
                                            int lane) {
    int c0 = (w >> 2) * 2;
#pragma unroll
    for (int cc = 0; cc < 2; ++cc) {
        int c = c0 + cc;
        short8_t bh0 = Bh[c * 64 + lane];
        short8_t bl0 = Bl[c * 64 + lane];
        short8_t bh1 = Bh[(4 + c) * 64 + lane];
        short8_t bl1 = Bl[(4 + c) * 64 + lane];
        f32x4 acc = {0.f, 0.f, 0.f, 0.f};
        acc = __builtin_amdgcn_mfma_f32_16x16x32_bf16(ah0, bh0, acc, 0, 0, 0);
        acc = __builtin_amdgcn_mfma_f32_16x16x32_bf16(al0, bh0, acc, 0, 0, 0);
        acc = __builtin_amdgcn_mfma_f32_16x16x32_bf16(ah0, bl0, acc, 0, 0, 0);
        acc = __builtin_amdgcn_mfma_f32_16x16x32_bf16(ah1, bh1, acc, 0, 0, 0);
        acc = __builtin_amdgcn_mfma_f32_16x16x32_bf16(al1, bh1, acc, 0, 0, 0);
        acc = __builtin_amdgcn_mfma_f32_16x16x32_bf16(ah1, bl1, acc, 0, 0, 0);
        int col = c * 16 + (lane & 15);
        float bb = bias[col];
#pragma unroll
        for (int r = 0; r < 4; ++r) {
            int row = (w & 3) * 16 + ((lane >> 4) << 2) + r;
            oT[row * OS + col] = acc[r] + bb;
        }
    }
}

// wave-scan helper (wave 0): counts -> excl prefix + total, stored in LDS
__device__ __forceinline__ void scan64(int cnt, int lane, int* pfxs, int* cnts,
                                       int* nps) {
    int val = cnt;
#pragma unroll
    for (int off = 1; off < 64; off <<= 1) {
        int v2 = __shfl_up(val, off);
        if (lane >= off) val += v2;
    }
    pfxs[lane] = val - cnt;
    cnts[lane] = cnt;
    if (lane == 63) nps[0] = val;
}

// ---------------------------------------------------------------------------
// Barrier-free per-wave fixup loop with NEXT-PAIR PREFETCH: the (it+1)
// pair entry + feature row load issue BEFORE consuming pair it, hiding the
// ~500-600cyc gather latency under the weight-load + FMA chain.
// ---------------------------------------------------------------------------
__device__ __forceinline__ void fixup_loop(const float* __restrict__ src,
                                           const float* __restrict__ Wbase,
                                           const int* __restrict__ pl, int np,
                                           float fsc[8][2][64],
                                           float* __restrict__ oT, int w,
                                           int lane) {
    int p = w;
    if (p >= np) return;
    int e = pl[p];
    float fv = src[(size_t)(e & 0x1FFFF) * 64 + lane];
    int it = 0;
#pragma unroll 1
    for (; p < np; p += 8, ++it) {
        // prefetch next pair (issued before current consumption)
        int en = 0;
        float fvn = 0.f;
        if (p + 8 < np) {
            en = pl[p + 8];
            fvn = src[(size_t)(en & 0x1FFFF) * 64 + lane];
        }
        int tag = (e >> 17) & 31, row = (e >> 23) & 63;
        int buf = it & 1;
        fsc[w][buf][lane] = fv;
        const float* wk = Wbase + (size_t)tag * 4096;  // [ci][co]
        float a0 = 0.f, a1 = 0.f, a2 = 0.f, a3 = 0.f;
#pragma unroll
        for (int c4 = 0; c4 < 16; ++c4) {
            f32x4 fb = *(f32x4*)&fsc[w][buf][c4 * 4];  // ds broadcast
            a0 += fb[0] * wk[(c4 * 4 + 0) * 64 + lane];
            a1 += fb[1] * wk[(c4 * 4 + 1) * 64 + lane];
            a2 += fb[2] * wk[(c4 * 4 + 2) * 64 + lane];
            a3 += fb[3] * wk[(c4 * 4 + 3) * 64 + lane];
        }
        atomicAdd(&oT[row * OS + lane], (a0 + a1) + (a2 + a3));
        e = en;
        fv = fvn;
    }
}

// ---------------------------------------------------------------------------
// conv1 fused (32-row tiles) + hidden conv2-weight prep tail.
// ---------------------------------------------------------------------------
__global__ __launch_bounds__(512) void conv1_fused_kernel(
    const int* __restrict__ coords, const float* __restrict__ feats,
    const float* __restrict__ W1, const float* __restrict__ W2,
    const unsigned short* __restrict__ Wpk1h,
    const unsigned short* __restrict__ Wpk1l, const float* __restrict__ b1,
    const unsigned short* __restrict__ grid, int* __restrict__ c2s,
    int* __restrict__ p2s, unsigned short* __restrict__ Wpk2h,
    unsigned short* __restrict__ Wpk2l, float* __restrict__ W2e,
    float* __restrict__ h, int n, int nblk1) {
    if (blockIdx.x >= nblk1) {  // ---- prep-tail blocks (no LDS, no barriers)
        int t = (blockIdx.x - nblk1) * 512 + threadIdx.x;
        if (t < 4096) {  // conv2 dense (self-parent fold) fragments
            int u = t;
            int fid = u >> 6, l = u & 63;
            int s = fid >> 3, kb = (fid >> 2) & 1, c = fid & 3;
            int s0 = (s >> 2) & 1, s1 = (s >> 1) & 1, s2 = s & 1;
#pragma unroll
            for (int e = 0; e < 8; ++e) {
                int ci = kb * 32 + ((l >> 4) << 3) + e;
                int co = c * 16 + (l & 15);
                float sum = 0.f;
                for (int o0 = -s0; o0 <= 1 - s0; ++o0)
                    for (int o1 = -s1; o1 <= 1 - s1; ++o1)
                        for (int o2 = -s2; o2 <= 1 - s2; ++o2) {
                            int k = (o0 + 1) * 9 + (o1 + 1) * 3 + (o2 + 1);
                            sum += W2[k * 4096 + ci * 64 + co];
                        }
                unsigned short hi, lo;
                split2(sum, hi, lo);
                Wpk2h[(size_t)u * 8 + e] = hi;
                Wpk2l[(size_t)u * 8 + e] = lo;
            }
        } else if (t < 4096 + 262144) {  // W2e fp32 fixup weights
            int r = t - 4096;
            int sd = r >> 12, e = r & 4095;
            int s = sd >> 3, d = sd & 7;
            int sa[3] = { (s >> 2) & 1, (s >> 1) & 1, s & 1 };
            int da[3] = { (d >> 2) & 1, (d >> 1) & 1, d & 1 };
            int lo_[3], hi_[3];
            for (int a = 0; a < 3; ++a) {
                int p = sa[a] - 1 + da[a];
                int l = 2 * p - sa[a];     if (l < -1) l = -1;
                int hh = 2 * p + 1 - sa[a]; if (hh > 1) hh = 1;
                lo_[a] = l; hi_[a] = hh;
            }
            float sum = 0.f;
            for (int o0 = lo_[0]; o0 <= hi_[0]; ++o0)
                for (int o1 = lo_[1]; o1 <= hi_[1]; ++o1)
                    for (int o2 = lo_[2]; o2 <= hi_[2]; ++o2) {
                        int k = (o0 + 1) * 9 + (o1 + 1) * 3 + (o2 + 1);
                        sum += W2[k * 4096 + e];
                    }
            W2e[(size_t)sd * 4096 + e] = sum;
        }
        return;
    }

    __shared__ __align__(16) float oT[32 * OS];
    __shared__ __align__(16) float fsc[8][2][64];
    __shared__ int plt[32 * 26];
    __shared__ int pl[832];
    __shared__ int pfxs[64], cnts_s[64], nps[1];
    int base = blockIdx.x * 32;
    int t = threadIdx.x, w = t >> 6, lane = t & 63;

    if (t < 64) {  // build: threads 0..31 (one row each); all of wave 0 scans
        int cnt = 0;
        if (t < 32) {
            int myv = base + t;
            if (myv < n) {
                int c0 = coords[3 * myv], c1v = coords[3 * myv + 1],
                    c2v = coords[3 * myv + 2];
                int n2[8] = {0, 0, 0, 0, 0, 0, 0, 0};
#pragma unroll 1
                for (int g = 0; g < 3; ++g) {
                    int jv9[9];
                    int kb = g * 9;
#pragma unroll
                    for (int u = 0; u < 9; ++u) {
                        int k = kb + u;
                        int o0 = k / 9 - 1, o1 = (k / 3) % 3 - 1,
                            o2 = k % 3 - 1;
                        int x0 = c0 + o0, x1 = c1v + o1, x2 = c2v + o2;
                        bool inb = (unsigned)x0 < D1 && (unsigned)x1 < D1 &&
                                   (unsigned)x2 < D1;
                        jv9[u] = inb ? (int)grid[(x0 * D1 + x1) * D1 + x2] : 0;
                    }
#pragma unroll
                    for (int u = 0; u < 9; ++u) {
                        int k = kb + u;
                        if (k == 13) continue;
                        int j1 = jv9[u];
                        if (j1 < 1 || j1 > n) continue;  // poison reject
                        int o0 = k / 9 - 1, o1 = (k / 3) % 3 - 1,
                            o2 = k % 3 - 1;
                        int x0 = c0 + o0, x1 = c1v + o1, x2 = c2v + o2;
                        int jj = j1 - 1;
                        if (coords[3 * jj] != x0 ||
                            coords[3 * jj + 1] != x1 ||
                            coords[3 * jj + 2] != x2)
                            continue;
                        plt[t * 26 + cnt] = jj | (k << 17);
                        ++cnt;
#pragma unroll
                        for (int s = 0; s < 8; ++s) {
                            int d0 = o0 + 1 - ((s >> 2) & 1);
                            int d1 = o1 + 1 - ((s >> 1) & 1);
                            int d2 = o2 + 1 - (s & 1);
                            if (((d0 | d1 | d2) & ~1) == 0) {
                                int d = (d0 << 2) | (d1 << 1) | d2;
                                p2s[((size_t)myv * 8 + s) * CAP2S + n2[s]] =
                                    jj | (d << 17);
                                ++n2[s];
                            }
                        }
                    }
                }
#pragma unroll
                for (int s = 0; s < 8; ++s) c2s[myv * 8 + s] = n2[s];
            }
        }
        scan64(cnt, lane, pfxs, cnts_s, nps);
    }

    int arow = base + (w & 1) * 16 + (lane & 15);
    if (arow >= n) arow = n - 1;
    short8_t ah0, al0, ah1, al1;
    load_split_A(feats, arow, lane, ah0, al0, ah1, al1);
    dense_mfma32(ah0, al0, ah1, al1, (const short8_t*)Wpk1h,
                 (const short8_t*)Wpk1l, b1, oT, w, lane);
    __syncthreads();

    {   // parallel compaction: 16 threads per row (32 rows)
        int row = t & 31, e0 = t >> 5;
        int cr = cnts_s[row], pf = pfxs[row];
        for (int e = e0; e < cr; e += 16)
            pl[pf + e] = plt[row * 26 + e] | (row << 23);
    }
    __syncthreads();

    fixup_loop(feats, W1, pl, nps[0], fsc, oT, w, lane);
    __syncthreads();

    {   // SiLU + coalesced store: 512 threads, 4 floats each over 32x64
        int r = t >> 4, c4 = (t & 15) * 4;
        if (base + r < n) {
            f32x4 v = *(f32x4*)&oT[r * OS + c4];
#pragma unroll
            for (int u = 0; u < 4; ++u) v[u] = silu(v[u]);
            *(f32x4*)&h[(size_t)(base + r) * 64 + c4] = v;
        }
    }
}

// ---------------------------------------------------------------------------
// conv2 fused: 1D grid with XCD tile-affinity swizzle.
//   Tm = idx%8; s = (idx/8)%8; T = (idx/64)*8 + Tm
// ---------------------------------------------------------------------------
__global__ __launch_bounds__(512) void conv2_fused_kernel(
    const float* __restrict__ h, const unsigned short* __restrict__ Wpk2h,
    const unsigned short* __restrict__ Wpk2l, const float* __restrict__ W2e,
    const float* __restrict__ b2, const int* __restrict__ c2s,
    const int* __restrict__ p2s, float* __restrict__ out, int n) {
    __shared__ __align__(16) float oT[64 * OS];
    __shared__ __align__(16) float fsc[8][2][64];
    __shared__ int pl[448];
    __shared__ int pfxs[64], cnts_s[64], nps[1];
    int idx = blockIdx.x;
    int Tm = idx & 7, s = (idx >> 3) & 7, T = (idx >> 6) * 8 + Tm;
    int base = T * 64;
    if (base >= n) return;
    int t = threadIdx.x, w = t >> 6, lane = t & 63;

    if (t < 64) {
        int cnt = (base + lane < n) ? c2s[(size_t)(base + lane) * 8 + s] : 0;
        scan64(cnt, lane, pfxs, cnts_s, nps);
    }

    int arow = base + (w & 3) * 16 + (lane & 15);
    if (arow >= n) arow = n - 1;
    short8_t ah0, al0, ah1, al1;
    load_split_A(h, arow, lane, ah0, al0, ah1, al1);
    dense_mfma8(ah0, al0, ah1, al1,
                (const short8_t*)Wpk2h + (size_t)s * 8 * 64,
                (const short8_t*)Wpk2l + (size_t)s * 8 * 64, b2, oT, w, lane);
    __syncthreads();

    {   // parallel compaction: 8 threads per row
        int row = t & 63, e0 = t >> 6;
        int cr = cnts_s[row], pf = pfxs[row];
        for (int e = e0; e < cr; e += 8)
            pl[pf + e] =
                p2s[((size_t)(base + row) * 8 + s) * CAP2S + e] | (row << 23);
    }
    __syncthreads();

    fixup_loop(h, W2e + (size_t)s * 8 * 4096, pl, nps[0], fsc, oT, w, lane);
    __syncthreads();

    {   // SiLU + coalesced store (out row = parent*8 + s)
        int r = t >> 3, c8 = (t & 7) * 8;
        if (base + r < n) {
#pragma unroll
            for (int jj = 0; jj < 2; ++jj) {
                f32x4 v = *(f32x4*)&oT[r * OS + c8 + jj * 4];
#pragma unroll
                for (int u = 0; u < 4; ++u) v[u] = silu(v[u]);
                *(f32x4*)&out[((size_t)(base + r) * 8 + s) * 64 + c8 + jj * 4] = v;
            }
        }
    }
}

// ---------------------------------------------------------------------------
extern "C" void kernel_launch(void* const* d_in, const int* in_sizes, int n_in,
                              void* d_out, int out_size, void* d_ws,
                              size_t ws_size, hipStream_t stream) {
    const int* coords = (const int*)d_in[0];
    const float* feats = (const float*)d_in[1];
    const float* W1 = (const float*)d_in[2];
    const float* b1 = (const float*)d_in[3];
    const float* W2 = (const float*)d_in[4];
    const float* b2 = (const float*)d_in[5];
    float* out = (float*)d_out;

    int n = in_sizes[0] / 3;   // 20000
    int nblk = (n + 63) / 64;  // 313 (conv2 tiles)
    int nblk1 = (n + 31) / 32; // 625 (conv1 tiles)

    char* ws = (char*)d_ws;
    size_t off = 0;
    auto alloc = [&](size_t bytes) {
        size_t o = off;
        off = (off + bytes + 255) & ~(size_t)255;
        return o;
    };
    unsigned short* grid1 = (unsigned short*)(ws + alloc((size_t)GRID_VOX * 2));
    float* h      = (float*)(ws + alloc((size_t)n * 64 * 4));     // 5.12 MB
    float* W2e    = (float*)(ws + alloc(64 * 4096 * 4));          // 1 MB
    unsigned short* Wpk1h = (unsigned short*)(ws + alloc(512 * 8 * 2));
    unsigned short* Wpk1l = (unsigned short*)(ws + alloc(512 * 8 * 2));
    unsigned short* Wpk2h = (unsigned short*)(ws + alloc(4096 * 8 * 2));
    unsigned short* Wpk2l = (unsigned short*)(ws + alloc(4096 * 8 * 2));
    int*   c2s    = (int*)(ws + alloc((size_t)n * 8 * 4));        // 0.64 MB
    int*   p2s    = (int*)(ws + alloc((size_t)n * 8 * CAP2S * 4)); // 5.12 MB

    // setupA: Wpk1 pack + grid scatter only (small, fast)
    setupA_kernel<<<(512 + n + 255) / 256, 256, 0, stream>>>(
        W1, coords, grid1, Wpk1h, Wpk1l, n);

    // conv1 (32-row tiles) + hidden conv2-weight prep (520 tail blocks)
    int prepBlocks = (4096 + 262144 + 511) / 512;  // 520
    conv1_fused_kernel<<<nblk1 + prepBlocks, 512, 0, stream>>>(
        coords, feats, W1, W2, Wpk1h, Wpk1l, b1, grid1, c2s, p2s, Wpk2h,
        Wpk2l, W2e, h, n, nblk1);

    int nTileGrp = (nblk + 7) / 8;  // 40
    conv2_fused_kernel<<<nTileGrp * 64, 512, 0, stream>>>(
        h, Wpk2h, Wpk2l, W2e, b2, c2s, p2s, out, n);
}